// Round 18
// baseline (202.625 us; speedup 1.0000x reference)
//
#include <hip/hip_runtime.h>
#include <stdint.h>

#define B_ 4096
#define D_ 1024
#define BM 128
#define BN 128
#define BK 64
#define NT 16            // K tiles (1024 / 64), consumed in pairs (K=128)
#define TINV 10.0f
#define LOG2E 1.4426950408889634f
#define KE (TINV * LOG2E)
#define INV_BM1 (1.0f / 4095.0f)
#define SC1 0x7F7F7F7F   // E8M0 unity scales (2^0) in all 4 bytes

typedef float f32x4 __attribute__((ext_vector_type(4)));
typedef int   i32x8 __attribute__((ext_vector_type(8)));

__device__ __forceinline__ unsigned short f2bf(float x) {
  uint32_t b = __float_as_uint(x);
  b += 0x7FFF + ((b >> 16) & 1);   // RNE
  return (unsigned short)(b >> 16);
}

// f32 -> OCP e4m3fn, round-nearest-even (|x| < 8 assumed; handles subnormals)
__device__ __forceinline__ uint8_t f2e4m3(float x) {
  uint32_t u = __float_as_uint(x);
  uint32_t s = (u >> 24) & 0x80;
  int e = (int)((u >> 23) & 0xFF) - 127;
  uint32_t m = u & 0x7FFFFF;
  if (e >= -6) {
    uint32_t mant = m >> 20;
    uint32_t rest = m & 0xFFFFF;
    uint32_t rnd = (rest > 0x80000u) || (rest == 0x80000u && (mant & 1));
    mant += rnd;
    uint32_t exp4 = (uint32_t)(e + 7);
    if (mant == 8) { mant = 0; exp4++; }
    return (uint8_t)(s | (exp4 << 3) | mant);
  } else {
    uint32_t M = 0x800000u | m;
    int sh = 20 + (-6 - e);
    if (sh > 31) return (uint8_t)s;
    uint32_t mant = M >> sh;
    uint32_t rest = M & ((1u << sh) - 1);
    uint32_t half = 1u << (sh - 1);
    uint32_t rnd = (rest > half) || (rest == half && (mant & 1));
    mant += rnd;
    return (uint8_t)(s | mant);
  }
}

__device__ __forceinline__ void gload16(const void* g, void* l) {
  __builtin_amdgcn_global_load_lds(
      (const __attribute__((address_space(1))) uint32_t*)g,
      (__attribute__((address_space(3))) uint32_t*)l, 16, 0, 0);
}

// ---------------- K1: L2-normalize rows, emit fp8 e4m3, K-PERMUTED layout -----
// Within each 64-k block, physical byte order is [g=0..3][h=0..1]: logical
// k = h*32 + g*8 + (0..7) stored at phys g*16 + h*8 + (0..7). Both A and B
// get the same permutation -> GEMM result unchanged (dot is k-perm-invariant).
__global__ __launch_bounds__(256) void k_normalize(const float* __restrict__ zis,
                                                   const float* __restrict__ zjs,
                                                   uint8_t* __restrict__ Aq,
                                                   uint8_t* __restrict__ Bq) {
  int r = blockIdx.x;
  const float* src;
  uint8_t* dst;
  if (r < B_) { src = zis + (size_t)r * D_; dst = Aq + (size_t)r * D_; }
  else        { src = zjs + (size_t)(r - B_) * D_; dst = Bq + (size_t)(r - B_) * D_; }
  int t = threadIdx.x;
  float4 v = reinterpret_cast<const float4*>(src)[t];
  float ss = v.x*v.x + v.y*v.y + v.z*v.z + v.w*v.w;
  #pragma unroll
  for (int o = 32; o >= 1; o >>= 1) ss += __shfl_down(ss, o);
  __shared__ float red[4];
  if ((t & 63) == 0) red[t >> 6] = ss;
  __syncthreads();
  float sc = rsqrtf(red[0] + red[1] + red[2] + red[3]);
  uchar4 o4;
  o4.x = f2e4m3(v.x * sc); o4.y = f2e4m3(v.y * sc);
  o4.z = f2e4m3(v.z * sc); o4.w = f2e4m3(v.w * sc);
  int k0 = t * 4;
  int blk = k0 >> 6, w64 = k0 & 63;
  int g = (w64 & 31) >> 3, h = (w64 >> 5) & 1;
  int phys = blk * 64 + g * 16 + h * 8 + (w64 & 7);
  *reinterpret_cast<uchar4*>(dst + phys) = o4;
}

// ---------------- K2: 128x128 MX-fp8 GEMM, K=128 MFMA, 8 waves, 64 KB LDS -----
// 8 waves 2M x 4N, per-wave 64x32 (4x2 16x16 frags). K-permuted operands:
// lane (fr,kq)'s per-tile fragment chunk = 16 CONTIGUOUS bytes at slot
// (kq^(fr&3))*16 -> one ds_read_b128 per tile-row, tuples fill directly.
// launch_bounds(512,1): 2 waves/SIMD -> 256-VGPR budget (128 cap was the
// spill cause in R15-R17).
__global__ __launch_bounds__(512, 1) void k_gemm(const uint8_t* __restrict__ A,
                                                 const uint8_t* __restrict__ B,
                                                 unsigned short* __restrict__ C,
                                                 float* __restrict__ diagp) {
  __shared__ uint8_t lds[4][16384];   // [slot][A:0..8192 | B:8192..16384]
  const int tid = threadIdx.x;
  const int wid = tid >> 6;         // 0..7
  const int lane = tid & 63;
  const int wm = wid >> 2;          // 0..1  (rows wm*64)
  const int wn = wid & 3;           // 0..3  (cols wn*32)
  const int bRow = blockIdx.y * BM;
  const int bCol = blockIdx.x * BN;
  const uint8_t* Ag = A + (size_t)bRow * D_;
  const uint8_t* Bg = B + (size_t)bCol * D_;

  // stage geometry: chunk = 16 rows x 64 B = 1 KB per gload16 (linear LDS dest).
  // source group pre-swizzled: (lane&3) ^ (row&3)  [both-sides rule]
  const int lrow = lane >> 2;
  const int scol = (((lane & 3) ^ (lrow & 3)) << 4);
  const size_t so = (size_t)(wid * 16 + lrow) * D_ + scol;

  // fragment-read geometry: row R at R*64, 16-B slot (kq ^ (R&3))*16
  const int fr = lane & 15;
  const int kq = lane >> 4;
  const int rdo = ((kq ^ (fr & 3)) << 4);

  f32x4 acc[4][2] = {};

#define STAGE(T, SL) {                                                        \
    gload16(Ag + (size_t)(T) * BK + so, &lds[SL][wid * 1024]);                \
    gload16(Bg + (size_t)(T) * BK + so, &lds[SL][8192 + wid * 1024]); }

  // ---- prologue: stage tiles 0..3 into slots 0..3; tiles 0,1 resident ----
  STAGE(0, 0); STAGE(1, 1); STAGE(2, 2); STAGE(3, 3);
  asm volatile("s_waitcnt vmcnt(4)" ::: "memory");   // drains tiles 0,1
  __builtin_amdgcn_sched_barrier(0);
  __builtin_amdgcn_s_barrier();
  __builtin_amdgcn_sched_barrier(0);

  for (int i = 0; i < 8; ++i) {
    const int s0 = (2 * i) & 3, s1 = (2 * i + 1) & 3;
    const uint8_t* L0 = lds[s0];
    const uint8_t* L1 = lds[s1];
    i32x8 av[4], bv[2];
    #pragma unroll
    for (int m = 0; m < 4; ++m) {
      int ro = (wm * 64 + m * 16 + fr) * 64 + rdo;
      int4 p = *reinterpret_cast<const int4*>(&L0[ro]);
      int4 q = *reinterpret_cast<const int4*>(&L1[ro]);
      av[m][0] = p.x; av[m][1] = p.y; av[m][2] = p.z; av[m][3] = p.w;
      av[m][4] = q.x; av[m][5] = q.y; av[m][6] = q.z; av[m][7] = q.w;
    }
    #pragma unroll
    for (int n = 0; n < 2; ++n) {
      int ro = 8192 + (wn * 32 + n * 16 + fr) * 64 + rdo;
      int4 p = *reinterpret_cast<const int4*>(&L0[ro]);
      int4 q = *reinterpret_cast<const int4*>(&L1[ro]);
      bv[n][0] = p.x; bv[n][1] = p.y; bv[n][2] = p.z; bv[n][3] = p.w;
      bv[n][4] = q.x; bv[n][5] = q.y; bv[n][6] = q.z; bv[n][7] = q.w;
    }
    // all waves' reads of s0,s1 retired -> safe to overwrite
    asm volatile("s_waitcnt lgkmcnt(0)" ::: "memory");
    __builtin_amdgcn_sched_barrier(0);
    __builtin_amdgcn_s_barrier();
    __builtin_amdgcn_sched_barrier(0);
    if (2 * i + 4 < NT) { STAGE(2 * i + 4, s0); STAGE(2 * i + 5, s1); }
    __builtin_amdgcn_s_setprio(1);
    #pragma unroll
    for (int m = 0; m < 4; ++m)
      #pragma unroll
      for (int n = 0; n < 2; ++n)
        acc[m][n] = __builtin_amdgcn_mfma_scale_f32_16x16x128_f8f6f4(
            av[m], bv[n], acc[m][n], 0, 0, 0, SC1, 0, SC1);
    __builtin_amdgcn_s_setprio(0);
    if (i < 6) {
      asm volatile("s_waitcnt vmcnt(4)" ::: "memory");   // drain prev iter's 4
    } else if (i == 6) {
      asm volatile("s_waitcnt vmcnt(0)" ::: "memory");
    }
    __builtin_amdgcn_sched_barrier(0);
    if (i < 7) {
      __builtin_amdgcn_s_barrier();
      __builtin_amdgcn_sched_barrier(0);
    }
  }

  // ---- epilogue: diag (f32) + packed bf16x2 C store ----
  const int fr4 = kq * 4;
  #pragma unroll
  for (int m = 0; m < 4; ++m)
    #pragma unroll
    for (int n = 0; n < 2; ++n)
      #pragma unroll
      for (int q = 0; q < 4; ++q) {
        float v = acc[m][n][q];
        int rg = bRow + wm * 64 + m * 16 + fr4 + q;
        int cg = bCol + wn * 32 + n * 16 + fr;
        if (rg == cg) diagp[rg] = v;
        float p = __shfl_xor(v, 1);
        if (!(lane & 1)) {
          uint32_t u = (uint32_t)f2bf(v) | ((uint32_t)f2bf(p) << 16);
          *reinterpret_cast<uint32_t*>(&C[(size_t)rg * B_ + cg]) = u;
        }
      }
#undef STAGE
}

// ---------------- K3: fused single-read pass, 1024 thr (4 waves/SIMD) ---------
__global__ __launch_bounds__(1024) void k_fused(const unsigned short* __restrict__ sim,
    const float* __restrict__ diag,
    const float* __restrict__ bI, const float* __restrict__ sI,
    const int* __restrict__ ids,
    float* __restrict__ LI, float* __restrict__ cmax_p,
    float* __restrict__ cE_p, float* __restrict__ cE2_p) {
  const int i0 = blockIdx.x * 16;
  const int t = threadIdx.x;
  const int w = t >> 6, lane = t & 63;
  __shared__ float rowPart[16][16][3];

  float cmax[4], cE[4], cE2[4];
  #pragma unroll
  for (int k = 0; k < 4; ++k) { cmax[k] = -3.4e38f; cE[k] = 0.f; cE2[k] = 0.f; }

  for (int r = 0; r < 16; ++r) {
    const unsigned short* sp = sim + (size_t)(i0 + r) * B_ + t * 4;
    uint2 u0 = *reinterpret_cast<const uint2*>(sp);
    float x[4];
    x[0] = __uint_as_float(u0.x << 16); x[1] = __uint_as_float(u0.x & 0xffff0000u);
    x[2] = __uint_as_float(u0.y << 16); x[3] = __uint_as_float(u0.y & 0xffff0000u);
    float rmx = -3.4e38f, rE = 0.f, rE2 = 0.f;
    #pragma unroll
    for (int k = 0; k < 4; ++k) {
      float e = exp2f(x[k] * KE);
      rmx = fmaxf(rmx, x[k]);
      rE += e;
      rE2 = fmaf(e, x[k], rE2);
      cmax[k] = fmaxf(cmax[k], x[k]);
      cE[k] += e;
      cE2[k] = fmaf(e, x[k], cE2[k]);
    }
    #pragma unroll
    for (int o = 32; o >= 1; o >>= 1) {
      rmx = fmaxf(rmx, __shfl_down(rmx, o));
      rE += __shfl_down(rE, o);
      rE2 += __shfl_down(rE2, o);
    }
    if (lane == 0) { rowPart[r][w][0] = rmx; rowPart[r][w][1] = rE; rowPart[r][w][2] = rE2; }
  }
  __syncthreads();
  if (t < 16) {
    int i = i0 + t;
    float mx = -3.4e38f, E = 0.f, E2 = 0.f;
    #pragma unroll
    for (int k = 0; k < 16; ++k) {
      mx = fmaxf(mx, rowPart[t][k][0]);
      E += rowPart[t][k][1];
      E2 += rowPart[t][k][2];
    }
    float dg = diag[i];
    float ed = exp2f(dg * KE);
    int id = ids[i];
    float oldb = bI[id];
    float newb = fmaxf((mx - dg) * TINV, oldb);
    float sc = exp2f(-(dg * TINV + newb) * LOG2E);
    float S1 = (E - ed) * sc;
    float S2 = (E2 - dg * E) * sc;
    float g = S1 * INV_BM1;
    float sn = 0.2f * sI[id] * exp2f((oldb - newb) * LOG2E) + 0.8f * g;
    LI[i] = S2 / fmaxf(sn, 1e-14f) * INV_BM1;
  }
  size_t base = (size_t)blockIdx.x * B_ + t * 4;
  #pragma unroll
  for (int k = 0; k < 4; ++k) {
    cmax_p[base + k] = cmax[k];
    cE_p[base + k]   = cE[k];
    cE2_p[base + k]  = cE2[k];
  }
}

// ---------------- K4: column reduce (512 blocks, 32 threads/col) ----------------
__global__ __launch_bounds__(256) void k_colred(
    const float* __restrict__ diag,
    const float* __restrict__ cmax_p, const float* __restrict__ cE_p,
    const float* __restrict__ cE2_p,
    const float* __restrict__ bT, const float* __restrict__ sT,
    const int* __restrict__ ids, const float* __restrict__ LI,
    float* __restrict__ partial) {
  const int t = threadIdx.x;
  const int cidx = t >> 5;          // 0..7 (col within block)
  const int sub = t & 31;
  const int j = blockIdx.x * 8 + cidx;
  float mx = -3.4e38f, E = 0.f, E2 = 0.f;
  #pragma unroll
  for (int k = 0; k < 8; ++k) {
    size_t o = (size_t)(sub + 32 * k) * B_ + j;
    mx = fmaxf(mx, cmax_p[o]);
    E += cE_p[o];
    E2 += cE2_p[o];
  }
  #pragma unroll
  for (int o = 16; o >= 1; o >>= 1) {
    mx = fmaxf(mx, __shfl_down(mx, o, 32));
    E += __shfl_down(E, o, 32);
    E2 += __shfl_down(E2, o, 32);
  }
  __shared__ float red[8];
  if (sub == 0) {
    float dg = diag[j];
    float ed = exp2f(dg * KE);
    int id = ids[j];
    float oldb = bT[id];
    float newb = fmaxf((mx - dg) * TINV, oldb);
    float sc = exp2f(-(dg * TINV + newb) * LOG2E);
    float S1 = (E - ed) * sc;
    float S2 = (E2 - dg * E) * sc;
    float g = S1 * INV_BM1;
    float sn = 0.2f * sT[id] * exp2f((oldb - newb) * LOG2E) + 0.8f * g;
    float lt = S2 / fmaxf(sn, 1e-14f) * INV_BM1;
    red[cidx] = (0.5f * LI[j] + 0.5f * lt) * (1.0f / (float)B_);
  }
  __syncthreads();
  if (t == 0) {
    float s = 0.f;
    #pragma unroll
    for (int k = 0; k < 8; ++k) s += red[k];
    partial[blockIdx.x] = s;
  }
}

// ---------------- K5: final reduce over 512 partials ----------------
__global__ void k_final2(const float* __restrict__ partial, float* __restrict__ out) {
  int t = threadIdx.x;
  float v = partial[t];
  #pragma unroll
  for (int o = 32; o >= 1; o >>= 1) v += __shfl_down(v, o);
  __shared__ float red[8];
  if ((t & 63) == 0) red[t >> 6] = v;
  __syncthreads();
  if (t == 0) {
    float s = 0.f;
    #pragma unroll
    for (int k = 0; k < 8; ++k) s += red[k];
    out[0] = s;
  }
}

extern "C" void kernel_launch(void* const* d_in, const int* in_sizes, int n_in,
                              void* d_out, int out_size, void* d_ws, size_t ws_size,
                              hipStream_t stream) {
  const float* zis = (const float*)d_in[0];
  const float* zjs = (const float*)d_in[1];
  const float* s_I = (const float*)d_in[2];
  const float* s_T = (const float*)d_in[3];
  const float* b_I = (const float*)d_in[4];
  const float* b_T = (const float*)d_in[5];
  const int*   ids = (const int*)d_in[6];

  char* ws = (char*)d_ws;
  size_t off = 0;
  auto alloc = [&](size_t bytes) -> void* {
    void* p = ws + off;
    off = (off + bytes + 255) & ~(size_t)255;
    return p;
  };
  uint8_t* Aq = (uint8_t*)alloc((size_t)B_ * D_);                      // 4 MB
  uint8_t* Bq = (uint8_t*)alloc((size_t)B_ * D_);                      // 4 MB
  unsigned short* sim = (unsigned short*)alloc((size_t)B_ * B_ * 2);   // 32 MB
  float* diag   = (float*)alloc(B_ * 4);
  float* cmax_p = (float*)alloc((size_t)256 * B_ * 4);                 // 4 MB each
  float* cE_p   = (float*)alloc((size_t)256 * B_ * 4);
  float* cE2_p  = (float*)alloc((size_t)256 * B_ * 4);
  float* LI     = (float*)alloc(B_ * 4);
  float* partial = (float*)alloc(512 * 4);

  k_normalize<<<2 * B_, 256, 0, stream>>>(zis, zjs, Aq, Bq);
  k_gemm<<<dim3(B_ / BN, B_ / BM), 512, 0, stream>>>(Aq, Bq, sim, diag);
  k_fused<<<256, 1024, 0, stream>>>(sim, diag, b_I, s_I, ids, LI, cmax_p, cE_p, cE2_p);
  k_colred<<<512, 256, 0, stream>>>(diag, cmax_p, cE_p, cE2_p, b_T, s_T, ids, LI, partial);
  k_final2<<<1, 512, 0, stream>>>(partial, (float*)d_out);
}

// Round 19
// 80.185 us; speedup vs baseline: 2.5270x; 2.5270x over previous
//
#include <hip/hip_runtime.h>
#include <stdint.h>

#define B_ 4096
#define D_ 1024
#define BM 256
#define BN 128
#define BK 64
#define NT 16            // K tiles (1024 / 64)
#define TINV 10.0f
#define LOG2E 1.4426950408889634f
#define KE (TINV * LOG2E)
#define INV_BM1 (1.0f / 4095.0f)

typedef float f32x4 __attribute__((ext_vector_type(4)));

__device__ __forceinline__ unsigned short f2bf(float x) {
  uint32_t b = __float_as_uint(x);
  b += 0x7FFF + ((b >> 16) & 1);   // RNE
  return (unsigned short)(b >> 16);
}

// f32 -> OCP e4m3fn, round-nearest-even (|x| < 8 assumed; handles subnormals)
__device__ __forceinline__ uint8_t f2e4m3(float x) {
  uint32_t u = __float_as_uint(x);
  uint32_t s = (u >> 24) & 0x80;
  int e = (int)((u >> 23) & 0xFF) - 127;
  uint32_t m = u & 0x7FFFFF;
  if (e >= -6) {
    uint32_t mant = m >> 20;
    uint32_t rest = m & 0xFFFFF;
    uint32_t rnd = (rest > 0x80000u) || (rest == 0x80000u && (mant & 1));
    mant += rnd;
    uint32_t exp4 = (uint32_t)(e + 7);
    if (mant == 8) { mant = 0; exp4++; }
    return (uint8_t)(s | (exp4 << 3) | mant);
  } else {
    uint32_t M = 0x800000u | m;
    int sh = 20 + (-6 - e);
    if (sh > 31) return (uint8_t)s;
    uint32_t mant = M >> sh;
    uint32_t rest = M & ((1u << sh) - 1);
    uint32_t half = 1u << (sh - 1);
    uint32_t rnd = (rest > half) || (rest == half && (mant & 1));
    mant += rnd;                       // carry to 8 == exp1/mant0 (2^-6), still correct
    return (uint8_t)(s | mant);
  }
}

__device__ __forceinline__ void gload16(const void* g, void* l) {
  __builtin_amdgcn_global_load_lds(
      (const __attribute__((address_space(1))) uint32_t*)g,
      (__attribute__((address_space(3))) uint32_t*)l, 16, 0, 0);
}

// ---------------- K1: L2-normalize rows, emit fp8 e4m3 ----------------
__global__ __launch_bounds__(256) void k_normalize(const float* __restrict__ zis,
                                                   const float* __restrict__ zjs,
                                                   uint8_t* __restrict__ Aq,
                                                   uint8_t* __restrict__ Bq) {
  int r = blockIdx.x;
  const float* src;
  uint8_t* dst;
  if (r < B_) { src = zis + (size_t)r * D_; dst = Aq + (size_t)r * D_; }
  else        { src = zjs + (size_t)(r - B_) * D_; dst = Bq + (size_t)(r - B_) * D_; }
  int t = threadIdx.x;
  float4 v = reinterpret_cast<const float4*>(src)[t];
  float ss = v.x*v.x + v.y*v.y + v.z*v.z + v.w*v.w;
  #pragma unroll
  for (int o = 32; o >= 1; o >>= 1) ss += __shfl_down(ss, o);
  __shared__ float red[4];
  if ((t & 63) == 0) red[t >> 6] = ss;
  __syncthreads();
  float sc = rsqrtf(red[0] + red[1] + red[2] + red[3]);
  uchar4 o4;
  o4.x = f2e4m3(v.x * sc); o4.y = f2e4m3(v.y * sc);
  o4.z = f2e4m3(v.z * sc); o4.w = f2e4m3(v.w * sc);
  reinterpret_cast<uchar4*>(dst)[t] = o4;
}

// ---------------- K2: 256x128 fp8 GEMM, BK=64, triple-buffered LDS (72 KB) ----
// R11 skeleton: 8 waves 4M x 2N, per-wave 64x64 (4x4 16x16 frags), 1 barrier/
// tile, vmcnt(3). fp8 e4m3 operands via mfma_f32_16x16x32_fp8_fp8 (bf16 rate,
// half the LDS/HBM bytes). Rows = 64 B; swizzle: byte bits4,5 ^= row bits2,3
// (even-group XOR -> 16B staging source stays contiguous; residual 2-way=free).
__global__ __launch_bounds__(512, 4) void k_gemm(const uint8_t* __restrict__ A,
                                                 const uint8_t* __restrict__ B,
                                                 unsigned short* __restrict__ C,
                                                 float* __restrict__ diagp) {
  __shared__ uint8_t lds[3][24576];   // [slot][A:0..16384 | B:16384..24576]
  const int tid = threadIdx.x;
  const int wid = tid >> 6;
  const int lane = tid & 63;
  const int wm = wid >> 1;          // 0..3
  const int wn = wid & 1;           // 0..1
  const int bRow = blockIdx.y * BM;
  const int bCol = blockIdx.x * BN;
  const uint8_t* Ag = A + (size_t)bRow * D_;
  const uint8_t* Bg = B + (size_t)bCol * D_;

  // stage geometry: chunk = 16 rows x 64 B = 1 KB per gload16.
  // source col pre-swizzled: scol = (lane&3)*16 ^ (lane&48)  [row bits 2,3]
  const int lrow = lane >> 2;
  const int scol = ((lane & 3) * 16) ^ (lane & 48);
  const size_t soA0 = (size_t)(wid * 32 + lrow) * D_ + scol;        // A chunk 2w
  const size_t soA1 = (size_t)(wid * 32 + 16 + lrow) * D_ + scol;   // A chunk 2w+1
  const size_t soB  = (size_t)(wid * 16 + lrow) * D_ + scol;        // B chunk w

  // fragment-read geometry: row R at R*64; k-bytes (ks*32+kq*8) ^ sx,
  // sx = (R bits 2,3) -> byte bits 4,5.
  const int fr = lane & 15;
  const int kq = lane >> 4;
  const int sx = (fr & 12) << 2;

  f32x4 acc[4][4] = {};

#define STAGE(T, SL) {                                                        \
    const uint8_t* gA_ = Ag + (size_t)(T) * BK;                               \
    const uint8_t* gB_ = Bg + (size_t)(T) * BK;                               \
    gload16(gA_ + soA0, &lds[SL][(2 * wid + 0) * 1024]);                      \
    gload16(gA_ + soA1, &lds[SL][(2 * wid + 1) * 1024]);                      \
    gload16(gB_ + soB,  &lds[SL][16384 + wid * 1024]); }

  // ---- prologue: stage tiles 0,1 into slots 0,1; drain tile 0 ----
  STAGE(0, 0); STAGE(1, 1);
  asm volatile("s_waitcnt vmcnt(3)" ::: "memory");
  __builtin_amdgcn_sched_barrier(0);
  __builtin_amdgcn_s_barrier();
  __builtin_amdgcn_sched_barrier(0);

  int sl = 0, sl2 = 2;               // sl = t%3 ; sl2 = (t+2)%3
  for (int t = 0; t < NT; ++t) {
    const uint8_t* Lb = lds[sl];
    long long a8[4][2], b8[4][2];
    #pragma unroll
    for (int m = 0; m < 4; ++m) {
      const uint8_t* rp = &Lb[(wm * 64 + m * 16 + fr) * 64];
      a8[m][0] = *reinterpret_cast<const long long*>(&rp[(kq * 8) ^ sx]);
      a8[m][1] = *reinterpret_cast<const long long*>(&rp[(32 + kq * 8) ^ sx]);
    }
    #pragma unroll
    for (int n = 0; n < 4; ++n) {
      const uint8_t* rp = &Lb[16384 + (wn * 64 + n * 16 + fr) * 64];
      b8[n][0] = *reinterpret_cast<const long long*>(&rp[(kq * 8) ^ sx]);
      b8[n][1] = *reinterpret_cast<const long long*>(&rp[(32 + kq * 8) ^ sx]);
    }
    if (t + 2 < NT) STAGE(t + 2, sl2);   // overwrites slot of t-1 (reads retired)
    __builtin_amdgcn_s_setprio(1);
    #pragma unroll
    for (int m = 0; m < 4; ++m)
      #pragma unroll
      for (int n = 0; n < 4; ++n) {
        acc[m][n] = __builtin_amdgcn_mfma_f32_16x16x32_fp8_fp8(
            a8[m][0], b8[n][0], acc[m][n], 0, 0, 0);
        acc[m][n] = __builtin_amdgcn_mfma_f32_16x16x32_fp8_fp8(
            a8[m][1], b8[n][1], acc[m][n], 0, 0, 0);
      }
    __builtin_amdgcn_s_setprio(0);
    if (t < NT - 2) {
      asm volatile("s_waitcnt vmcnt(3)" ::: "memory");   // t+1 fully staged
    } else if (t == NT - 2) {
      asm volatile("s_waitcnt vmcnt(0)" ::: "memory");
    }
    __builtin_amdgcn_sched_barrier(0);
    if (t < NT - 1) {
      __builtin_amdgcn_s_barrier();
      __builtin_amdgcn_sched_barrier(0);
    }
    sl = (sl == 2) ? 0 : sl + 1;
    sl2 = (sl2 == 2) ? 0 : sl2 + 1;
  }

  // ---- epilogue: diag (f32) + packed bf16x2 C store ----
  const int fr4 = kq * 4;
  #pragma unroll
  for (int m = 0; m < 4; ++m)
    #pragma unroll
    for (int n = 0; n < 4; ++n)
      #pragma unroll
      for (int q = 0; q < 4; ++q) {
        float v = acc[m][n][q];
        int rg = bRow + wm * 64 + m * 16 + fr4 + q;
        int cg = bCol + wn * 64 + n * 16 + fr;
        if (rg == cg) diagp[rg] = v;
        float p = __shfl_xor(v, 1);
        if (!(lane & 1)) {
          uint32_t u = (uint32_t)f2bf(v) | ((uint32_t)f2bf(p) << 16);
          *reinterpret_cast<uint32_t*>(&C[(size_t)rg * B_ + cg]) = u;
        }
      }
#undef STAGE
}

// ---------------- K3: fused single-read pass, 1024 thr (4 waves/SIMD) ---------
__global__ __launch_bounds__(1024) void k_fused(const unsigned short* __restrict__ sim,
    const float* __restrict__ diag,
    const float* __restrict__ bI, const float* __restrict__ sI,
    const int* __restrict__ ids,
    float* __restrict__ LI, float* __restrict__ cmax_p,
    float* __restrict__ cE_p, float* __restrict__ cE2_p) {
  const int i0 = blockIdx.x * 16;
  const int t = threadIdx.x;
  const int w = t >> 6, lane = t & 63;
  __shared__ float rowPart[16][16][3];

  float cmax[4], cE[4], cE2[4];
  #pragma unroll
  for (int k = 0; k < 4; ++k) { cmax[k] = -3.4e38f; cE[k] = 0.f; cE2[k] = 0.f; }

  for (int r = 0; r < 16; ++r) {
    const unsigned short* sp = sim + (size_t)(i0 + r) * B_ + t * 4;
    uint2 u0 = *reinterpret_cast<const uint2*>(sp);
    float x[4];
    x[0] = __uint_as_float(u0.x << 16); x[1] = __uint_as_float(u0.x & 0xffff0000u);
    x[2] = __uint_as_float(u0.y << 16); x[3] = __uint_as_float(u0.y & 0xffff0000u);
    float rmx = -3.4e38f, rE = 0.f, rE2 = 0.f;
    #pragma unroll
    for (int k = 0; k < 4; ++k) {
      float e = exp2f(x[k] * KE);
      rmx = fmaxf(rmx, x[k]);
      rE += e;
      rE2 = fmaf(e, x[k], rE2);
      cmax[k] = fmaxf(cmax[k], x[k]);
      cE[k] += e;
      cE2[k] = fmaf(e, x[k], cE2[k]);
    }
    #pragma unroll
    for (int o = 32; o >= 1; o >>= 1) {
      rmx = fmaxf(rmx, __shfl_down(rmx, o));
      rE += __shfl_down(rE, o);
      rE2 += __shfl_down(rE2, o);
    }
    if (lane == 0) { rowPart[r][w][0] = rmx; rowPart[r][w][1] = rE; rowPart[r][w][2] = rE2; }
  }
  __syncthreads();
  if (t < 16) {
    int i = i0 + t;
    float mx = -3.4e38f, E = 0.f, E2 = 0.f;
    #pragma unroll
    for (int k = 0; k < 16; ++k) {
      mx = fmaxf(mx, rowPart[t][k][0]);
      E += rowPart[t][k][1];
      E2 += rowPart[t][k][2];
    }
    float dg = diag[i];
    float ed = exp2f(dg * KE);
    int id = ids[i];
    float oldb = bI[id];
    float newb = fmaxf((mx - dg) * TINV, oldb);
    float sc = exp2f(-(dg * TINV + newb) * LOG2E);
    float S1 = (E - ed) * sc;
    float S2 = (E2 - dg * E) * sc;
    float g = S1 * INV_BM1;
    float sn = 0.2f * sI[id] * exp2f((oldb - newb) * LOG2E) + 0.8f * g;
    LI[i] = S2 / fmaxf(sn, 1e-14f) * INV_BM1;
  }
  size_t base = (size_t)blockIdx.x * B_ + t * 4;
  #pragma unroll
  for (int k = 0; k < 4; ++k) {
    cmax_p[base + k] = cmax[k];
    cE_p[base + k]   = cE[k];
    cE2_p[base + k]  = cE2[k];
  }
}

// ---------------- K4: column reduce (512 blocks, 32 threads/col) ----------------
__global__ __launch_bounds__(256) void k_colred(
    const float* __restrict__ diag,
    const float* __restrict__ cmax_p, const float* __restrict__ cE_p,
    const float* __restrict__ cE2_p,
    const float* __restrict__ bT, const float* __restrict__ sT,
    const int* __restrict__ ids, const float* __restrict__ LI,
    float* __restrict__ partial) {
  const int t = threadIdx.x;
  const int cidx = t >> 5;          // 0..7 (col within block)
  const int sub = t & 31;
  const int j = blockIdx.x * 8 + cidx;
  float mx = -3.4e38f, E = 0.f, E2 = 0.f;
  #pragma unroll
  for (int k = 0; k < 8; ++k) {
    size_t o = (size_t)(sub + 32 * k) * B_ + j;
    mx = fmaxf(mx, cmax_p[o]);
    E += cE_p[o];
    E2 += cE2_p[o];
  }
  #pragma unroll
  for (int o = 16; o >= 1; o >>= 1) {
    mx = fmaxf(mx, __shfl_down(mx, o, 32));
    E += __shfl_down(E, o, 32);
    E2 += __shfl_down(E2, o, 32);
  }
  __shared__ float red[8];
  if (sub == 0) {
    float dg = diag[j];
    float ed = exp2f(dg * KE);
    int id = ids[j];
    float oldb = bT[id];
    float newb = fmaxf((mx - dg) * TINV, oldb);
    float sc = exp2f(-(dg * TINV + newb) * LOG2E);
    float S1 = (E - ed) * sc;
    float S2 = (E2 - dg * E) * sc;
    float g = S1 * INV_BM1;
    float sn = 0.2f * sT[id] * exp2f((oldb - newb) * LOG2E) + 0.8f * g;
    float lt = S2 / fmaxf(sn, 1e-14f) * INV_BM1;
    red[cidx] = (0.5f * LI[j] + 0.5f * lt) * (1.0f / (float)B_);
  }
  __syncthreads();
  if (t == 0) {
    float s = 0.f;
    #pragma unroll
    for (int k = 0; k < 8; ++k) s += red[k];
    partial[blockIdx.x] = s;
  }
}

// ---------------- K5: final reduce over 512 partials ----------------
__global__ void k_final2(const float* __restrict__ partial, float* __restrict__ out) {
  int t = threadIdx.x;
  float v = partial[t];
  #pragma unroll
  for (int o = 32; o >= 1; o >>= 1) v += __shfl_down(v, o);
  __shared__ float red[8];
  if ((t & 63) == 0) red[t >> 6] = v;
  __syncthreads();
  if (t == 0) {
    float s = 0.f;
    #pragma unroll
    for (int k = 0; k < 8; ++k) s += red[k];
    out[0] = s;
  }
}

extern "C" void kernel_launch(void* const* d_in, const int* in_sizes, int n_in,
                              void* d_out, int out_size, void* d_ws, size_t ws_size,
                              hipStream_t stream) {
  const float* zis = (const float*)d_in[0];
  const float* zjs = (const float*)d_in[1];
  const float* s_I = (const float*)d_in[2];
  const float* s_T = (const float*)d_in[3];
  const float* b_I = (const float*)d_in[4];
  const float* b_T = (const float*)d_in[5];
  const int*   ids = (const int*)d_in[6];

  char* ws = (char*)d_ws;
  size_t off = 0;
  auto alloc = [&](size_t bytes) -> void* {
    void* p = ws + off;
    off = (off + bytes + 255) & ~(size_t)255;
    return p;
  };
  uint8_t* Aq = (uint8_t*)alloc((size_t)B_ * D_);                      // 4 MB
  uint8_t* Bq = (uint8_t*)alloc((size_t)B_ * D_);                      // 4 MB
  unsigned short* sim = (unsigned short*)alloc((size_t)B_ * B_ * 2);   // 32 MB
  float* diag   = (float*)alloc(B_ * 4);
  float* cmax_p = (float*)alloc((size_t)256 * B_ * 4);                 // 4 MB each
  float* cE_p   = (float*)alloc((size_t)256 * B_ * 4);
  float* cE2_p  = (float*)alloc((size_t)256 * B_ * 4);
  float* LI     = (float*)alloc(B_ * 4);
  float* partial = (float*)alloc(512 * 4);

  k_normalize<<<2 * B_, 256, 0, stream>>>(zis, zjs, Aq, Bq);
  k_gemm<<<dim3(B_ / BN, B_ / BM), 512, 0, stream>>>(Aq, Bq, sim, diag);
  k_fused<<<256, 1024, 0, stream>>>(sim, diag, b_I, s_I, ids, LI, cmax_p, cE_p, cE2_p);
  k_colred<<<512, 256, 0, stream>>>(diag, cmax_p, cE_p, cE2_p, b_T, s_T, ids, LI, partial);
  k_final2<<<1, 512, 0, stream>>>(partial, (float*)d_out);
}